// Round 12
// baseline (307.475 us; speedup 1.0000x reference)
//
#include <hip/hip_runtime.h>
#include <hip/hip_bf16.h>
#include <math.h>

#define HIDDEN 1280
#define HEADS 16
#define HD 80           // head dim
#define HALF 40
#define BB 2
#define NN 2048
#define MROWS (BB * NN) // 4096
// 1/sqrt(80) * log2(e): scores come out in log2 domain -> exp2 directly
#define QSCALE ((float)(0.11180339887498949 * 1.4426950408889634))

typedef __attribute__((ext_vector_type(8))) _Float16 f16x8;
typedef __attribute__((ext_vector_type(4))) float f32x4;

#define AS1 __attribute__((address_space(1)))
#define AS3 __attribute__((address_space(3)))

// Split fp32 into fp16 hi + fp16 lo (hi+lo carries ~22 mantissa bits).
__device__ __forceinline__ void splitf16(float x, ushort& hi, ushort& lo) {
    _Float16 h = (_Float16)x;
    _Float16 l = (_Float16)(x - (float)h);
    hi = __builtin_bit_cast(ushort, h);
    lo = __builtin_bit_cast(ushort, l);
}

__device__ __forceinline__ ushort f2h(float x) {
    _Float16 h = (_Float16)x;
    return __builtin_bit_cast(ushort, h);
}

// ---------------------------------------------------------------------------
// Fused prep kernel: split x + transpose qkv_w + transpose proj_w.
// ---------------------------------------------------------------------------
__device__ __forceinline__ void tsplit_tile(
    const float* __restrict__ W, ushort* __restrict__ T, int K, int N,
    int n0, int k0, float (*s)[33], int tid)
{
    {
        int tn = tid & 31, tk = tid >> 5;
        #pragma unroll
        for (int i = 0; i < 4; ++i)
            s[tk + i * 8][tn] = W[(size_t)(k0 + tk + i * 8) * N + n0 + tn];
    }
    __syncthreads();
    {
        int tk = tid & 31, tn = tid >> 5;
        #pragma unroll
        for (int i = 0; i < 4; ++i)
            T[(size_t)(n0 + tn + i * 8) * K + k0 + tk] = f2h(s[tk][tn + i * 8]);
    }
}

__global__ __launch_bounds__(256) void prep_kernel(
    const float* __restrict__ x, ushort* __restrict__ a_hi,
    ushort* __restrict__ a_lo,
    const float* __restrict__ qkv_w, ushort* __restrict__ wT,
    const float* __restrict__ proj_w, ushort* __restrict__ pT)
{
    __shared__ float s[32][33];
    const int tid = threadIdx.x;
    const int id = blockIdx.x;

    if (id < 5120) {
        int i = id * 256 + tid;
        float4 v = ((const float4*)x)[i];
        ushort4 h, l;
        splitf16(v.x, h.x, l.x);
        splitf16(v.y, h.y, l.y);
        splitf16(v.z, h.z, l.z);
        splitf16(v.w, h.w, l.w);
        ((ushort4*)a_hi)[i] = h;
        ((ushort4*)a_lo)[i] = l;
    } else if (id < 9920) {
        int id2 = id - 5120;
        int n0 = (id2 % 120) * 32, k0 = (id2 / 120) * 32;
        tsplit_tile(qkv_w, wT, HIDDEN, 3 * HIDDEN, n0, k0, s, tid);
    } else {
        int id2 = id - 9920;
        int n0 = (id2 % 40) * 32, k0 = (id2 / 40) * 32;
        tsplit_tile(proj_w, pT, HIDDEN, HIDDEN, n0, k0, s, tid);
    }
}

// ---------------------------------------------------------------------------
// fp16x2 MFMA GEMM 128x128 v2 (proj GEMM) — round-8 winner (kept): double-
// buffered (48 KB, 3 blocks/CU), stage(t+1) first, compiler-scheduled frag
// reads/MFMAs, one vmcnt(0)+barrier per tile. ~27 us.
// ---------------------------------------------------------------------------
#define BM 128
#define BN 128
#define BK 32

__global__ __launch_bounds__(256) void gemm_f16x2_kernel(
    const ushort* __restrict__ Ahi, const ushort* __restrict__ Alo,
    const ushort* __restrict__ Bh,
    const float* __restrict__ bias, float* __restrict__ C,
    int M, int N, int K)
{
    __shared__ __align__(16) ushort lds[2 * 12288];   // 49152 B

    const int tid = threadIdx.x;
    const int wid = tid >> 6;
    const int lane = tid & 63;
    const int col0 = blockIdx.x * BN;
    const int row0 = blockIdx.y * BM;
    const int wy = wid >> 1, wx = wid & 1;
    const int lrow = lane >> 2;
    const int lchunk = lane & 3;
    const int q = lane >> 4;
    const int r = lane & 15;

    // 24 segments (3 tiles x 8), 6 per wave — precomputed base addressing
    const ushort* gsrc[6];
    int ldst[6];
    #pragma unroll
    for (int i = 0; i < 6; ++i) {
        int s = wid + i * 4;
        int tile = s >> 3, t = s & 7;
        const ushort* src = (tile == 0) ? Ahi : (tile == 1) ? Alo : Bh;
        int srow = (tile < 2) ? row0 : col0;
        gsrc[i] = src + (size_t)(srow + t * 16 + lrow) * K + lchunk * 8;
        ldst[i] = tile * 4096 + t * 512 + lane * 8;
    }

    const int NT = K / BK;

    // prologue: stage tile 0 -> buf0
    #pragma unroll
    for (int i = 0; i < 6; ++i)
        __builtin_amdgcn_global_load_lds((const AS1 unsigned int*)(gsrc[i]),
            (AS3 unsigned int*)(lds + ldst[i]), 16, 0, 0);
    asm volatile("s_waitcnt vmcnt(0)" ::: "memory");
    __builtin_amdgcn_s_barrier();

    f32x4 acc[4][4] = {};
    int cb = 0;

    for (int t = 0; t < NT; ++t) {
        const ushort* base = lds + cb;
        ushort* nbuf = lds + (12288 - cb);
        if (t + 1 < NT) {
            const int ko = (t + 1) * BK;
            #pragma unroll
            for (int i = 0; i < 6; ++i)
                __builtin_amdgcn_global_load_lds((const AS1 unsigned int*)(gsrc[i] + ko),
                    (AS3 unsigned int*)(nbuf + ldst[i]), 16, 0, 0);
        }

        f16x8 ah[4], al[4], bf[4];
        #pragma unroll
        for (int i = 0; i < 4; ++i) {
            int arow = wy * 64 + i * 16 + r;
            ah[i] = *(const f16x8*)(base + 0 * 4096 + arow * 32 + q * 8);
            al[i] = *(const f16x8*)(base + 1 * 4096 + arow * 32 + q * 8);
            int brow = wx * 64 + i * 16 + r;
            bf[i] = *(const f16x8*)(base + 2 * 4096 + brow * 32 + q * 8);
        }
        #pragma unroll
        for (int i = 0; i < 4; ++i) {
            #pragma unroll
            for (int j = 0; j < 4; ++j) {
                acc[i][j] = __builtin_amdgcn_mfma_f32_16x16x32_f16(al[i], bf[j], acc[i][j], 0, 0, 0);
                acc[i][j] = __builtin_amdgcn_mfma_f32_16x16x32_f16(ah[i], bf[j], acc[i][j], 0, 0, 0);
            }
        }

        asm volatile("s_waitcnt vmcnt(0)" ::: "memory");
        __builtin_amdgcn_s_barrier();
        cb = 12288 - cb;
    }

    #pragma unroll
    for (int i = 0; i < 4; ++i) {
        #pragma unroll
        for (int j = 0; j < 4; ++j) {
            int col = col0 + wx * 64 + j * 16 + r;
            float b = bias[col];
            #pragma unroll
            for (int v = 0; v < 4; ++v) {
                int row = row0 + wy * 64 + i * 16 + q * 4 + v;
                C[(size_t)row * N + col] = acc[i][j][v] + b;
            }
        }
    }
}

// ---------------------------------------------------------------------------
// 256x128 8-wave fp16x2 GEMM v2 (QKV GEMM) — measured-best 4-phase structure
// (81.5-84 us, MfmaUtil 42-43%, 0 conflicts). Do not de-pessimize (round 8
// showed the phase barriers are load-bearing at 8 waves).
// ---------------------------------------------------------------------------
__global__ __launch_bounds__(512, 4) void gemm_f16x2_256x128_kernel(
    const ushort* __restrict__ Ahi, const ushort* __restrict__ Alo,
    const ushort* __restrict__ Bh,
    const float* __restrict__ bias, float* __restrict__ C,
    int M, int N, int K, int nbx)
{
    __shared__ __align__(16) ushort lds[2 * 20480];   // 81920 B

    const int tid = threadIdx.x;
    const int wid = tid >> 6;
    const int lane = tid & 63;
    const int q = lane >> 4, r = lane & 15;
    const int wr = wid >> 1;      // 0..3: 64-row band
    const int wc = wid & 1;       // 0..1: 64-col band

    // T1: XCD-aware block swizzle (valid: grid % 8 == 0)
    int id = blockIdx.x;
    {
        int nwg = gridDim.x;
        if ((nwg & 7) == 0) {
            int c = nwg >> 3;
            id = (id & 7) * c + (id >> 3);
        }
    }
    const int row0 = (id / nbx) * 256;
    const int col0 = (id % nbx) * 128;

    // --- staging: 5 global_load_lds per K-tile per wave ---
    const ushort* gsrc[5];
    int ldst[5];
    #pragma unroll
    for (int j = 0; j < 5; ++j) {
        if (j < 4) {
            int p = j >> 1;
            int rloc = wid * 32 + (j & 1) * 16 + (lane >> 2);
            int sl = (lane & 3) ^ ((rloc >> 1) & 3);
            const ushort* base = p ? Alo : Ahi;
            gsrc[j] = base + (size_t)(row0 + rloc) * K + sl * 8;
            ldst[j] = p * 8192 + (wid * 32 + (j & 1) * 16) * 32 + lane * 8;
        } else {
            int rloc = wid * 16 + (lane >> 2);
            int sl = (lane & 3) ^ ((rloc >> 1) & 3);
            gsrc[4] = Bh + (size_t)(col0 + rloc) * K + sl * 8;
            ldst[4] = 16384 + wid * 512 + lane * 8;
        }
    }

    const int NT = K / 32;

    // prologue: stage tile 0 -> buf0
    #pragma unroll
    for (int j = 0; j < 5; ++j)
        __builtin_amdgcn_global_load_lds((const AS1 unsigned int*)(gsrc[j]),
            (AS3 unsigned int*)(lds + ldst[j]), 16, 0, 0);
    asm volatile("s_waitcnt vmcnt(0)" ::: "memory");
    __builtin_amdgcn_s_barrier();

    const int soff = (q ^ ((r >> 1) & 3)) * 8;
    const int arow0 = wr * 64 + r;     // + m*16
    const int brow0 = wc * 64 + r;     // + n*16

    f32x4 acc[4][4] = {};
    f16x8 ah[4], al[4], bf[2];

    int cb = 0;
    for (int t = 0; t < NT; ++t) {
        const ushort* A0 = lds + cb;
        const ushort* A1 = lds + cb + 8192;
        const ushort* Bp = lds + cb + 16384;
        ushort* nbuf = lds + (20480 - cb);
        const bool st = (t + 1 < NT);
        const int ko = (t + 1) * 32;

        // ---- phase 1: n0-1 ----
        #pragma unroll
        for (int m = 0; m < 4; ++m) {
            int ro = (arow0 + m * 16) * 32 + soff;
            ah[m] = *(const f16x8*)(A0 + ro);
            al[m] = *(const f16x8*)(A1 + ro);
        }
        #pragma unroll
        for (int n = 0; n < 2; ++n)
            bf[n] = *(const f16x8*)(Bp + (brow0 + n * 16) * 32 + soff);
        if (st) {
            __builtin_amdgcn_global_load_lds((const AS1 unsigned int*)(gsrc[0] + ko),
                (AS3 unsigned int*)(nbuf + ldst[0]), 16, 0, 0);
            __builtin_amdgcn_global_load_lds((const AS1 unsigned int*)(gsrc[1] + ko),
                (AS3 unsigned int*)(nbuf + ldst[1]), 16, 0, 0);
            __builtin_amdgcn_global_load_lds((const AS1 unsigned int*)(gsrc[2] + ko),
                (AS3 unsigned int*)(nbuf + ldst[2]), 16, 0, 0);
        }
        __builtin_amdgcn_s_barrier();
        asm volatile("s_waitcnt lgkmcnt(0)" ::: "memory");
        __builtin_amdgcn_sched_barrier(0);
        __builtin_amdgcn_s_setprio(1);
        #pragma unroll
        for (int m = 0; m < 4; ++m) {
            #pragma unroll
            for (int n = 0; n < 2; ++n) {
                acc[m][n] = __builtin_amdgcn_mfma_f32_16x16x32_f16(al[m], bf[n], acc[m][n], 0, 0, 0);
                acc[m][n] = __builtin_amdgcn_mfma_f32_16x16x32_f16(ah[m], bf[n], acc[m][n], 0, 0, 0);
            }
        }
        __builtin_amdgcn_s_setprio(0);
        __builtin_amdgcn_s_barrier();

        // ---- phase 2: n2-3 ----
        #pragma unroll
        for (int n = 0; n < 2; ++n)
            bf[n] = *(const f16x8*)(Bp + (brow0 + (n + 2) * 16) * 32 + soff);
        if (st) {
            __builtin_amdgcn_global_load_lds((const AS1 unsigned int*)(gsrc[3] + ko),
                (AS3 unsigned int*)(nbuf + ldst[3]), 16, 0, 0);
            __builtin_amdgcn_global_load_lds((const AS1 unsigned int*)(gsrc[4] + ko),
                (AS3 unsigned int*)(nbuf + ldst[4]), 16, 0, 0);
        }
        __builtin_amdgcn_s_barrier();
        asm volatile("s_waitcnt lgkmcnt(0)" ::: "memory");
        __builtin_amdgcn_sched_barrier(0);
        __builtin_amdgcn_s_setprio(1);
        #pragma unroll
        for (int m = 0; m < 4; ++m) {
            #pragma unroll
            for (int n = 0; n < 2; ++n) {
                acc[m][n + 2] = __builtin_amdgcn_mfma_f32_16x16x32_f16(al[m], bf[n], acc[m][n + 2], 0, 0, 0);
                acc[m][n + 2] = __builtin_amdgcn_mfma_f32_16x16x32_f16(ah[m], bf[n], acc[m][n + 2], 0, 0, 0);
            }
        }
        __builtin_amdgcn_s_setprio(0);
        asm volatile("s_waitcnt vmcnt(0)" ::: "memory");
        __builtin_amdgcn_s_barrier();
        cb = 20480 - cb;
    }

    // epilogue: bias + store
    #pragma unroll
    for (int m = 0; m < 4; ++m) {
        #pragma unroll
        for (int n = 0; n < 4; ++n) {
            int col = col0 + wc * 64 + n * 16 + r;
            float b = bias[col];
            #pragma unroll
            for (int v = 0; v < 4; ++v) {
                int row = row0 + wr * 64 + m * 16 + q * 4 + v;
                C[(size_t)row * N + col] = acc[m][n][v] + b;
            }
        }
    }
}

// ---------------------------------------------------------------------------
// RoPE + scale + fp16 convert + head-major relayout. (unchanged)
// ---------------------------------------------------------------------------
__global__ __launch_bounds__(256) void rope_split_kernel(
    const float* __restrict__ qkv, const float* __restrict__ cos_t,
    const float* __restrict__ sin_t,
    ushort* __restrict__ qf, ushort* __restrict__ kf,
    ushort* __restrict__ vt)
{
    __shared__ float s_v[64][84];
    const int tid = threadIdx.x;
    const int b = blockIdx.z, h = blockIdx.y;
    const int n0 = blockIdx.x * 64;
    const int bh = b * HEADS + h;

    // V tile -> LDS (coalesced float4 loads)
    #pragma unroll
    for (int i = 0; i < 5; ++i) {
        int u = tid + i * 256;
        int n = u / 20, c = u % 20;
        const float* src = qkv + (size_t)(b * NN + n0 + n) * 3840 + 2 * HIDDEN + h * HD + c * 4;
        *(float4*)(&s_v[n][c * 4]) = *(const float4*)src;
    }

    // q,k RoPE + fp16: 640 units, each = (token n, 4-wide d group in [0,40))
    for (int u = tid; u < 640; u += 256) {
        int n = u / 10, p = u % 10;
        int d = p * 4;
        int ng = n0 + n;
        size_t rowb = (size_t)(b * NN + ng) * 3840;
        float4 c0 = *(const float4*)(cos_t + ng * HD + d);
        float4 c1 = *(const float4*)(cos_t + ng * HD + d + HALF);
        float4 s0 = *(const float4*)(sin_t + ng * HD + d);
        float4 s1 = *(const float4*)(sin_t + ng * HD + d + HALF);
        size_t qo = ((size_t)bh * NN + ng) * 96;
        // q (scaled by QSCALE so scores are in log2 domain)
        {
            float4 x0 = *(const float4*)(qkv + rowb + h * HD + d);
            float4 x1 = *(const float4*)(qkv + rowb + h * HD + d + HALF);
            ushort4 h4a, h4b;
            h4a.x = f2h((x0.x * c0.x - x1.x * s0.x) * QSCALE);
            h4a.y = f2h((x0.y * c0.y - x1.y * s0.y) * QSCALE);
            h4a.z = f2h((x0.z * c0.z - x1.z * s0.z) * QSCALE);
            h4a.w = f2h((x0.w * c0.w - x1.w * s0.w) * QSCALE);
            h4b.x = f2h((x1.x * c1.x + x0.x * s1.x) * QSCALE);
            h4b.y = f2h((x1.y * c1.y + x0.y * s1.y) * QSCALE);
            h4b.z = f2h((x1.z * c1.z + x0.z * s1.z) * QSCALE);
            h4b.w = f2h((x1.w * c1.w + x0.w * s1.w) * QSCALE);
            *(ushort4*)(qf + qo + d) = h4a;
            *(ushort4*)(qf + qo + d + HALF) = h4b;
        }
        // k (unscaled)
        {
            float4 x0 = *(const float4*)(qkv + rowb + HIDDEN + h * HD + d);
            float4 x1 = *(const float4*)(qkv + rowb + HIDDEN + h * HD + d + HALF);
            ushort4 h4a, h4b;
            h4a.x = f2h(x0.x * c0.x - x1.x * s0.x);
            h4a.y = f2h(x0.y * c0.y - x1.y * s0.y);
            h4a.z = f2h(x0.z * c0.z - x1.z * s0.z);
            h4a.w = f2h(x0.w * c0.w - x1.w * s0.w);
            h4b.x = f2h(x1.x * c1.x + x0.x * s1.x);
            h4b.y = f2h(x1.y * c1.y + x0.y * s1.y);
            h4b.z = f2h(x1.z * c1.z + x0.z * s1.z);
            h4b.w = f2h(x1.w * c1.w + x0.w * s1.w);
            *(ushort4*)(kf + qo + d) = h4a;
            *(ushort4*)(kf + qo + d + HALF) = h4b;
        }
    }

    // zero the d=80..95 pad for q and k. 256 units: which(1b) x n(6b) x part(1b)
    {
        int which = tid >> 7;
        int u = tid & 127;
        int n = u >> 1, part = u & 1;
        size_t o = ((size_t)bh * NN + n0 + n) * 96 + 80 + part * 8;
        uint4 z = {0u, 0u, 0u, 0u};
        if (which == 0) *(uint4*)(qf + o) = z;
        else            *(uint4*)(kf + o) = z;
    }
    __syncthreads();

    // V^T write (fp16): unit = (d, 16-token chunk)
    for (int u = tid; u < 320; u += 256) {
        int d = u >> 2, nc = u & 3;
        ushort hs[16];
        #pragma unroll
        for (int kk = 0; kk < 16; ++kk)
            hs[kk] = f2h(s_v[nc * 16 + kk][d]);
        size_t o = ((size_t)bh * HD + d) * NN + n0 + nc * 16;
        uint4 w0, w1;
        w0.x = (uint)hs[0] | ((uint)hs[1] << 16);
        w0.y = (uint)hs[2] | ((uint)hs[3] << 16);
        w0.z = (uint)hs[4] | ((uint)hs[5] << 16);
        w0.w = (uint)hs[6] | ((uint)hs[7] << 16);
        w1.x = (uint)hs[8] | ((uint)hs[9] << 16);
        w1.y = (uint)hs[10] | ((uint)hs[11] << 16);
        w1.z = (uint)hs[12] | ((uint)hs[13] << 16);
        w1.w = (uint)hs[14] | ((uint)hs[15] << 16);
        *(uint4*)(vt + o) = w0;
        *(uint4*)(vt + o + 8) = w1;
    }
}

// ---------------------------------------------------------------------------
// MFMA flash attention v8: swapped QK^T + packed-b64 P roundtrip.
// (Round-10 submission; bench infra failed before measurement. Re-audited:
// swapped C-layout, swizzle involutions, l-reduction lane mapping, and
// barrier uniformity all check out. Resubmitting unchanged.)
// v6 model (validated: predicted 82 us = measured): LDS-port-bound, with the
// P scatter costing 16 scalar ds_write_b16 per wave-iter. v8: compute
// sc = mfma(K, Q, sc) so each lane owns one whole q-row; P writes become
// 4x ds_write_b64. P matrix and oacc bit-identical; l sum order ulp-level.
// ---------------------------------------------------------------------------
__global__ __launch_bounds__(512, 4) void attn_mfma_kernel(
    const ushort* __restrict__ qf, const ushort* __restrict__ kf,
    const ushort* __restrict__ vt,
    ushort* __restrict__ ao_hi, ushort* __restrict__ ao_lo)
{
    __shared__ __align__(16) ushort lds[34816];   // 69632 B
    // buf0: [0,13312) = K0 [64][128] (8192) | V0 [80][64] (5120)
    // buf1: [13312,26624)
    // p_s : [26624,34816) = [128 rows][64 fp16], 16B-granule swizzled
    ushort* p_s = lds + 26624;

    const int tid = threadIdx.x;
    const int wave = tid >> 6, lane = tid & 63;
    const int quad = lane >> 4, r = lane & 15;
    const int b = blockIdx.z, h = blockIdx.y;
    const int bh = b * HEADS + h;
    const int q0 = blockIdx.x * 128;

    const size_t kb = (size_t)bh * NN * 96;
    const size_t vb = (size_t)bh * HD * NN;

    // ---- staging precompute: seg s = wave + 8*i, i = 0..3 (26 segs) ----
    const ushort* gptr[4];
    int ldso[4];
    #pragma unroll
    for (int i = 0; i < 4; ++i) {
        int s = wave + i * 8;
        if (s < 16) {
            int row = s * 4 + (lane >> 4);
            int t = lane & 15;
            int g = t ^ (row & 7);
            if (g >= 12) g = 0;
            gptr[i] = kf + kb + (size_t)row * 96 + g * 8;
            ldso[i] = s * 512 + lane * 8;
        } else if (s < 26) {
            int ts = s - 16;
            gptr[i] = vt + vb + (size_t)(ts * 8 + (lane >> 3)) * NN
                      + (size_t)(((lane & 7) ^ (lane >> 3)) * 8);
            ldso[i] = 8192 + ts * 512 + lane * 8;
        } else {
            gptr[i] = nullptr;
            ldso[i] = 0;
        }
    }

    // Q a-frags from [bh][n][96] fp16 (pre-scaled by QSCALE, pad zero)
    f16x8 qfr[3];
    #pragma unroll
    for (int c = 0; c < 3; ++c) {
        size_t o = ((size_t)bh * NN + q0 + wave * 16 + r) * 96 + c * 32 + quad * 8;
        qfr[c] = *(const f16x8*)(qf + o);
    }

    f32x4 oacc[5] = {};
    float l_lane = 0.0f;

    // per-lane p_s addressing (row = wave*16 + r, wave-private)
    const int prow = (wave * 16 + r) * 64;
    const int r7 = r & 7;

    // prologue: stage tile 0 -> buf0
    #pragma unroll
    for (int i = 0; i < 4; ++i) {
        int s = wave + i * 8;
        if (s < 26) {
            __builtin_amdgcn_global_load_lds((const AS1 unsigned int*)gptr[i],
                (AS3 unsigned int*)(lds + ldso[i]), 16, 0, 0);
            gptr[i] += (s < 16) ? 6144 : 64;
        }
    }
    asm volatile("s_waitcnt vmcnt(0)" ::: "memory");
    __builtin_amdgcn_s_barrier();

    int cur = 0;
    for (int j0 = 0; j0 < NN; j0 += 64) {
        const int nxt = 13312 - cur;
        // issue stage(j+1) -> other buffer (free since end of iter j-1)
        if (j0 + 64 < NN) {
            #pragma unroll
            for (int i = 0; i < 4; ++i) {
                int s = wave + i * 8;
                if (s < 26) {
                    __builtin_amdgcn_global_load_lds((const AS1 unsigned int*)gptr[i],
                        (AS3 unsigned int*)(lds + nxt + ldso[i]), 16, 0, 0);
                    gptr[i] += (s < 16) ? 6144 : 64;
                }
            }
        }

        const ushort* k_s = lds + cur;
        const _Float16* v_s = (const _Float16*)(lds + cur + 8192);

        // QK^T, SWAPPED operands: sc[jt][v] = S[q=wave*16+r][kt=jt*16+quad*4+v]
        // (scores bit-identical to unswapped; only lane placement changes)
        f32x4 sc[4] = {};
        __builtin_amdgcn_s_setprio(1);
        #pragma unroll
        for (int jt = 0; jt < 4; ++jt) {
            f16x8 kbf[3];
            int j = jt * 16 + r;
            #pragma unroll
            for (int c = 0; c < 3; ++c) {
                int ch = (c * 4 + quad) ^ r7;
                kbf[c] = *(const f16x8*)(k_s + j * 128 + ch * 8);
            }
            #pragma unroll
            for (int c = 0; c < 3; ++c)
                sc[jt] = __builtin_amdgcn_mfma_f32_16x16x32_f16(kbf[c], qfr[c], sc[jt], 0, 0, 0);
        }
        __builtin_amdgcn_s_setprio(0);

        // softmax: p = exp2(s); lane owns one q-row's 16 k-slots.
        // Per jt: pack 4 contiguous-k fp16 -> one b64 write (was 16x b16).
        #pragma unroll
        for (int jt = 0; jt < 4; ++jt) {
            float p0 = __builtin_amdgcn_exp2f(sc[jt][0]);
            float p1 = __builtin_amdgcn_exp2f(sc[jt][1]);
            float p2 = __builtin_amdgcn_exp2f(sc[jt][2]);
            float p3 = __builtin_amdgcn_exp2f(sc[jt][3]);
            l_lane += p0;
            l_lane += p1;
            l_lane += p2;
            l_lane += p3;
            uint2 w;
            w.x = (uint)f2h(p0) | ((uint)f2h(p1) << 16);
            w.y = (uint)f2h(p2) | ((uint)f2h(p3) << 16);
            // granule (16B = 8 fp16) index: jt*2 + (quad>>1), swizzled ^ r7;
            // 8B half within granule: (quad&1)
            int off = prow + (((jt * 2 + (quad >> 1)) ^ r7) * 8) + (quad & 1) * 4;
            *(uint2*)(p_s + off) = w;
        }

        // P a-frags: row wave*16+r, k-chunk cc*32+quad*8 (granule cc*4+quad,
        // same swizzle involution)
        f16x8 pa[2];
        #pragma unroll
        for (int cc = 0; cc < 2; ++cc) {
            int gp = ((cc * 4 + quad) ^ r7) * 8;
            pa[cc] = *(const f16x8*)(p_s + prow + gp);
        }

        // PV with V^T b-frags (chunk-swizzled reads — unchanged)
        __builtin_amdgcn_s_setprio(1);
        #pragma unroll
        for (int dt = 0; dt < 5; ++dt)
            #pragma unroll
            for (int cc = 0; cc < 2; ++cc) {
                int ck = (cc * 4 + quad) ^ r7;
                f16x8 vbf = *(const f16x8*)(v_s + (dt * 16 + r) * 64 + ck * 8);
                oacc[dt] = __builtin_amdgcn_mfma_f32_16x16x32_f16(pa[cc], vbf, oacc[dt], 0, 0, 0);
            }
        __builtin_amdgcn_s_setprio(0);

        // staging for j+1 had the whole compute phase to land; drain + sync
        asm volatile("s_waitcnt vmcnt(0)" ::: "memory");
        __builtin_amdgcn_s_barrier();
        cur = nxt;
    }

    // l reduction: lane holds partial for row wave*16+r; the 4 quad-copies
    // of each r hold disjoint k-slots -> sum across lanes r, r+16, r+32, r+48.
    float lt = l_lane;
    lt += __shfl_xor(lt, 16);
    lt += __shfl_xor(lt, 32);
    // redistribute: epilogue needs inv_l for row wave*16 + quad*4 + v, whose
    // total lives at lane (quad*4+v) (quad0 copy; all copies equal).
    float inv_l[4];
    #pragma unroll
    for (int v = 0; v < 4; ++v)
        inv_l[v] = 1.0f / __shfl(lt, quad * 4 + v);

    // epilogue: normalize + fp16-split into LDS [128][80] hi/lo, uint4 stores
    __syncthreads();
    #pragma unroll
    for (int v = 0; v < 4; ++v) {
        int row = wave * 16 + quad * 4 + v;
        #pragma unroll
        for (int dt = 0; dt < 5; ++dt) {
            float o = oacc[dt][v] * inv_l[v];
            ushort hh, ll;
            splitf16(o, hh, ll);
            lds[row * 80 + dt * 16 + r] = hh;
            lds[10240 + row * 80 + dt * 16 + r] = ll;
        }
    }
    __syncthreads();
    {
        size_t gbase = ((size_t)b * NN + q0) * HIDDEN + h * HD;
        #pragma unroll
        for (int i = 0; i < 5; ++i) {
            int u = tid + i * 512;            // 0..2559
            int plane = u / 1280, idx = u % 1280;
            int row = idx / 10, part = idx % 10;
            uint4 w = *(const uint4*)(lds + plane * 10240 + idx * 8);
            ushort* dst = (plane ? ao_lo : ao_hi) + gbase + (size_t)row * HIDDEN + part * 8;
            *(uint4*)dst = w;
        }
    }
}

// ---------------------------------------------------------------------------
extern "C" void kernel_launch(void* const* d_in, const int* in_sizes, int n_in,
                              void* d_out, int out_size, void* d_ws, size_t ws_size,
                              hipStream_t stream)
{
    const float* x      = (const float*)d_in[0];
    const float* cos_t  = (const float*)d_in[1];
    const float* sin_t  = (const float*)d_in[2];
    const float* qkv_w  = (const float*)d_in[3];
    const float* qkv_b  = (const float*)d_in[4];
    const float* proj_w = (const float*)d_in[5];
    const float* proj_b = (const float*)d_in[6];
    float* out = (float*)d_out;

    char* ws = (char*)d_ws;
    // layout (bytes), phase-based reuse:
    //   [0, 62914560)           qkv fp32 (gemm1 out; dead after rope_split)
    //       -> ao_hi @0 (10485760), ao_lo @10485760 (attn out, fp16 hi/lo)
    //   [62914560, 72744960)    wT fp16 (qkv_w^T); after gemm1:
    //       -> vt fp16 @62914560 (10485760, ends 73400320)
    //   [82575360, 103546880)   x split fp16 hi/lo (gemm1 A); after gemm1:
    //       -> qf @83886080 (12582912), kf @96468992 (ends 109051904)
    //   [109051904, 112328704)  pT fp16 (proj_w^T)
    float*  qkv   = (float*)ws;
    ushort* ao_hi = (ushort*)ws;
    ushort* ao_lo = (ushort*)(ws + 10485760);
    ushort* wT    = (ushort*)(ws + 62914560);
    ushort* vt    = (ushort*)(ws + 62914560);
    ushort* a_hi  = (ushort*)(ws + 82575360);
    ushort* a_lo  = (ushort*)(ws + 93061120);
    ushort* q_f   = (ushort*)(ws + 83886080);
    ushort* k_f   = (ushort*)(ws + 96468992);
    ushort* pT    = (ushort*)(ws + 109051904);

    // 1) fused prep: split x -> hi/lo, transpose qkv_w -> wT, proj_w -> pT
    prep_kernel<<<dim3(11520), 256, 0, stream>>>(
        x, a_hi, a_lo, qkv_w, wT, proj_w, pT);

    // 2) qkv = x @ qkv_w + qkv_b   (256x128 v2 4-phase — measured best)
    gemm_f16x2_256x128_kernel<<<dim3((MROWS / 256) * (3 * HIDDEN / 128)), 512, 0, stream>>>(
        a_hi, a_lo, wT, qkv_b, qkv, MROWS, 3 * HIDDEN, HIDDEN, 3 * HIDDEN / 128);

    // 3) RoPE + fp16 relayout (overwrites wT and x-split regions — both dead)
    rope_split_kernel<<<dim3(NN / 64, HEADS, BB), 256, 0, stream>>>(
        qkv, cos_t, sin_t, q_f, k_f, vt);

    // 4) MFMA flash attention v8 (swapped QK + packed P roundtrip)
    attn_mfma_kernel<<<dim3(NN / 128, HEADS, BB), 512, 0, stream>>>(
        q_f, k_f, vt, ao_hi, ao_lo);

    // 5) out = attn_out @ proj_w + proj_b  (128^2 double-buffered, ~27 us)
    gemm_f16x2_kernel<<<dim3(HIDDEN / BN, MROWS / BM), 256, 0, stream>>>(
        ao_hi, ao_lo, pT, proj_b, out, MROWS, HIDDEN, HIDDEN);
}

// Round 13
// 301.614 us; speedup vs baseline: 1.0194x; 1.0194x over previous
//
#include <hip/hip_runtime.h>
#include <hip/hip_bf16.h>
#include <math.h>

#define HIDDEN 1280
#define HEADS 16
#define HD 80           // head dim
#define HALF 40
#define BB 2
#define NN 2048
#define MROWS (BB * NN) // 4096
// 1/sqrt(80) * log2(e): scores come out in log2 domain -> exp2 directly
#define QSCALE ((float)(0.11180339887498949 * 1.4426950408889634))

typedef __attribute__((ext_vector_type(8))) _Float16 f16x8;
typedef __attribute__((ext_vector_type(4))) float f32x4;

#define AS1 __attribute__((address_space(1)))
#define AS3 __attribute__((address_space(3)))

// Split fp32 into fp16 hi + fp16 lo (hi+lo carries ~22 mantissa bits).
__device__ __forceinline__ void splitf16(float x, ushort& hi, ushort& lo) {
    _Float16 h = (_Float16)x;
    _Float16 l = (_Float16)(x - (float)h);
    hi = __builtin_bit_cast(ushort, h);
    lo = __builtin_bit_cast(ushort, l);
}

__device__ __forceinline__ ushort f2h(float x) {
    _Float16 h = (_Float16)x;
    return __builtin_bit_cast(ushort, h);
}

// ---------------------------------------------------------------------------
// Fused prep kernel: split x + transpose qkv_w + transpose proj_w.
// ---------------------------------------------------------------------------
__device__ __forceinline__ void tsplit_tile(
    const float* __restrict__ W, ushort* __restrict__ T, int K, int N,
    int n0, int k0, float (*s)[33], int tid)
{
    {
        int tn = tid & 31, tk = tid >> 5;
        #pragma unroll
        for (int i = 0; i < 4; ++i)
            s[tk + i * 8][tn] = W[(size_t)(k0 + tk + i * 8) * N + n0 + tn];
    }
    __syncthreads();
    {
        int tk = tid & 31, tn = tid >> 5;
        #pragma unroll
        for (int i = 0; i < 4; ++i)
            T[(size_t)(n0 + tn + i * 8) * K + k0 + tk] = f2h(s[tk][tn + i * 8]);
    }
}

__global__ __launch_bounds__(256) void prep_kernel(
    const float* __restrict__ x, ushort* __restrict__ a_hi,
    ushort* __restrict__ a_lo,
    const float* __restrict__ qkv_w, ushort* __restrict__ wT,
    const float* __restrict__ proj_w, ushort* __restrict__ pT)
{
    __shared__ float s[32][33];
    const int tid = threadIdx.x;
    const int id = blockIdx.x;

    if (id < 5120) {
        int i = id * 256 + tid;
        float4 v = ((const float4*)x)[i];
        ushort4 h, l;
        splitf16(v.x, h.x, l.x);
        splitf16(v.y, h.y, l.y);
        splitf16(v.z, h.z, l.z);
        splitf16(v.w, h.w, l.w);
        ((ushort4*)a_hi)[i] = h;
        ((ushort4*)a_lo)[i] = l;
    } else if (id < 9920) {
        int id2 = id - 5120;
        int n0 = (id2 % 120) * 32, k0 = (id2 / 120) * 32;
        tsplit_tile(qkv_w, wT, HIDDEN, 3 * HIDDEN, n0, k0, s, tid);
    } else {
        int id2 = id - 9920;
        int n0 = (id2 % 40) * 32, k0 = (id2 / 40) * 32;
        tsplit_tile(proj_w, pT, HIDDEN, HIDDEN, n0, k0, s, tid);
    }
}

// ---------------------------------------------------------------------------
// fp16x2 MFMA GEMM 128x128 v2 (proj GEMM) — round-8 winner (kept).
// ---------------------------------------------------------------------------
#define BM 128
#define BN 128
#define BK 32

__global__ __launch_bounds__(256) void gemm_f16x2_kernel(
    const ushort* __restrict__ Ahi, const ushort* __restrict__ Alo,
    const ushort* __restrict__ Bh,
    const float* __restrict__ bias, float* __restrict__ C,
    int M, int N, int K)
{
    __shared__ __align__(16) ushort lds[2 * 12288];   // 49152 B

    const int tid = threadIdx.x;
    const int wid = tid >> 6;
    const int lane = tid & 63;
    const int col0 = blockIdx.x * BN;
    const int row0 = blockIdx.y * BM;
    const int wy = wid >> 1, wx = wid & 1;
    const int lrow = lane >> 2;
    const int lchunk = lane & 3;
    const int q = lane >> 4;
    const int r = lane & 15;

    const ushort* gsrc[6];
    int ldst[6];
    #pragma unroll
    for (int i = 0; i < 6; ++i) {
        int s = wid + i * 4;
        int tile = s >> 3, t = s & 7;
        const ushort* src = (tile == 0) ? Ahi : (tile == 1) ? Alo : Bh;
        int srow = (tile < 2) ? row0 : col0;
        gsrc[i] = src + (size_t)(srow + t * 16 + lrow) * K + lchunk * 8;
        ldst[i] = tile * 4096 + t * 512 + lane * 8;
    }

    const int NT = K / BK;

    #pragma unroll
    for (int i = 0; i < 6; ++i)
        __builtin_amdgcn_global_load_lds((const AS1 unsigned int*)(gsrc[i]),
            (AS3 unsigned int*)(lds + ldst[i]), 16, 0, 0);
    asm volatile("s_waitcnt vmcnt(0)" ::: "memory");
    __builtin_amdgcn_s_barrier();

    f32x4 acc[4][4] = {};
    int cb = 0;

    for (int t = 0; t < NT; ++t) {
        const ushort* base = lds + cb;
        ushort* nbuf = lds + (12288 - cb);
        if (t + 1 < NT) {
            const int ko = (t + 1) * BK;
            #pragma unroll
            for (int i = 0; i < 6; ++i)
                __builtin_amdgcn_global_load_lds((const AS1 unsigned int*)(gsrc[i] + ko),
                    (AS3 unsigned int*)(nbuf + ldst[i]), 16, 0, 0);
        }

        f16x8 ah[4], al[4], bf[4];
        #pragma unroll
        for (int i = 0; i < 4; ++i) {
            int arow = wy * 64 + i * 16 + r;
            ah[i] = *(const f16x8*)(base + 0 * 4096 + arow * 32 + q * 8);
            al[i] = *(const f16x8*)(base + 1 * 4096 + arow * 32 + q * 8);
            int brow = wx * 64 + i * 16 + r;
            bf[i] = *(const f16x8*)(base + 2 * 4096 + brow * 32 + q * 8);
        }
        #pragma unroll
        for (int i = 0; i < 4; ++i) {
            #pragma unroll
            for (int j = 0; j < 4; ++j) {
                acc[i][j] = __builtin_amdgcn_mfma_f32_16x16x32_f16(al[i], bf[j], acc[i][j], 0, 0, 0);
                acc[i][j] = __builtin_amdgcn_mfma_f32_16x16x32_f16(ah[i], bf[j], acc[i][j], 0, 0, 0);
            }
        }

        asm volatile("s_waitcnt vmcnt(0)" ::: "memory");
        __builtin_amdgcn_s_barrier();
        cb = 12288 - cb;
    }

    #pragma unroll
    for (int i = 0; i < 4; ++i) {
        #pragma unroll
        for (int j = 0; j < 4; ++j) {
            int col = col0 + wx * 64 + j * 16 + r;
            float b = bias[col];
            #pragma unroll
            for (int v = 0; v < 4; ++v) {
                int row = row0 + wy * 64 + i * 16 + q * 4 + v;
                C[(size_t)row * N + col] = acc[i][j][v] + b;
            }
        }
    }
}

// ---------------------------------------------------------------------------
// 256x128 8-wave fp16x2 GEMM v2 (QKV GEMM) — measured-best 4-phase structure.
// ---------------------------------------------------------------------------
__global__ __launch_bounds__(512, 4) void gemm_f16x2_256x128_kernel(
    const ushort* __restrict__ Ahi, const ushort* __restrict__ Alo,
    const ushort* __restrict__ Bh,
    const float* __restrict__ bias, float* __restrict__ C,
    int M, int N, int K, int nbx)
{
    __shared__ __align__(16) ushort lds[2 * 20480];   // 81920 B

    const int tid = threadIdx.x;
    const int wid = tid >> 6;
    const int lane = tid & 63;
    const int q = lane >> 4, r = lane & 15;
    const int wr = wid >> 1;
    const int wc = wid & 1;

    int id = blockIdx.x;
    {
        int nwg = gridDim.x;
        if ((nwg & 7) == 0) {
            int c = nwg >> 3;
            id = (id & 7) * c + (id >> 3);
        }
    }
    const int row0 = (id / nbx) * 256;
    const int col0 = (id % nbx) * 128;

    const ushort* gsrc[5];
    int ldst[5];
    #pragma unroll
    for (int j = 0; j < 5; ++j) {
        if (j < 4) {
            int p = j >> 1;
            int rloc = wid * 32 + (j & 1) * 16 + (lane >> 2);
            int sl = (lane & 3) ^ ((rloc >> 1) & 3);
            const ushort* base = p ? Alo : Ahi;
            gsrc[j] = base + (size_t)(row0 + rloc) * K + sl * 8;
            ldst[j] = p * 8192 + (wid * 32 + (j & 1) * 16) * 32 + lane * 8;
        } else {
            int rloc = wid * 16 + (lane >> 2);
            int sl = (lane & 3) ^ ((rloc >> 1) & 3);
            gsrc[4] = Bh + (size_t)(col0 + rloc) * K + sl * 8;
            ldst[4] = 16384 + wid * 512 + lane * 8;
        }
    }

    const int NT = K / 32;

    #pragma unroll
    for (int j = 0; j < 5; ++j)
        __builtin_amdgcn_global_load_lds((const AS1 unsigned int*)(gsrc[j]),
            (AS3 unsigned int*)(lds + ldst[j]), 16, 0, 0);
    asm volatile("s_waitcnt vmcnt(0)" ::: "memory");
    __builtin_amdgcn_s_barrier();

    const int soff = (q ^ ((r >> 1) & 3)) * 8;
    const int arow0 = wr * 64 + r;
    const int brow0 = wc * 64 + r;

    f32x4 acc[4][4] = {};
    f16x8 ah[4], al[4], bf[2];

    int cb = 0;
    for (int t = 0; t < NT; ++t) {
        const ushort* A0 = lds + cb;
        const ushort* A1 = lds + cb + 8192;
        const ushort* Bp = lds + cb + 16384;
        ushort* nbuf = lds + (20480 - cb);
        const bool st = (t + 1 < NT);
        const int ko = (t + 1) * 32;

        // ---- phase 1: n0-1 ----
        #pragma unroll
        for (int m = 0; m < 4; ++m) {
            int ro = (arow0 + m * 16) * 32 + soff;
            ah[m] = *(const f16x8*)(A0 + ro);
            al[m] = *(const f16x8*)(A1 + ro);
        }
        #pragma unroll
        for (int n = 0; n < 2; ++n)
            bf[n] = *(const f16x8*)(Bp + (brow0 + n * 16) * 32 + soff);
        if (st) {
            __builtin_amdgcn_global_load_lds((const AS1 unsigned int*)(gsrc[0] + ko),
                (AS3 unsigned int*)(nbuf + ldst[0]), 16, 0, 0);
            __builtin_amdgcn_global_load_lds((const AS1 unsigned int*)(gsrc[1] + ko),
                (AS3 unsigned int*)(nbuf + ldst[1]), 16, 0, 0);
            __builtin_amdgcn_global_load_lds((const AS1 unsigned int*)(gsrc[2] + ko),
                (AS3 unsigned int*)(nbuf + ldst[2]), 16, 0, 0);
        }
        __builtin_amdgcn_s_barrier();
        asm volatile("s_waitcnt lgkmcnt(0)" ::: "memory");
        __builtin_amdgcn_sched_barrier(0);
        __builtin_amdgcn_s_setprio(1);
        #pragma unroll
        for (int m = 0; m < 4; ++m) {
            #pragma unroll
            for (int n = 0; n < 2; ++n) {
                acc[m][n] = __builtin_amdgcn_mfma_f32_16x16x32_f16(al[m], bf[n], acc[m][n], 0, 0, 0);
                acc[m][n] = __builtin_amdgcn_mfma_f32_16x16x32_f16(ah[m], bf[n], acc[m][n], 0, 0, 0);
            }
        }
        __builtin_amdgcn_s_setprio(0);
        __builtin_amdgcn_s_barrier();

        // ---- phase 2: n2-3 ----
        #pragma unroll
        for (int n = 0; n < 2; ++n)
            bf[n] = *(const f16x8*)(Bp + (brow0 + (n + 2) * 16) * 32 + soff);
        if (st) {
            __builtin_amdgcn_global_load_lds((const AS1 unsigned int*)(gsrc[3] + ko),
                (AS3 unsigned int*)(nbuf + ldst[3]), 16, 0, 0);
            __builtin_amdgcn_global_load_lds((const AS1 unsigned int*)(gsrc[4] + ko),
                (AS3 unsigned int*)(nbuf + ldst[4]), 16, 0, 0);
        }
        __builtin_amdgcn_s_barrier();
        asm volatile("s_waitcnt lgkmcnt(0)" ::: "memory");
        __builtin_amdgcn_sched_barrier(0);
        __builtin_amdgcn_s_setprio(1);
        #pragma unroll
        for (int m = 0; m < 4; ++m) {
            #pragma unroll
            for (int n = 0; n < 2; ++n) {
                acc[m][n + 2] = __builtin_amdgcn_mfma_f32_16x16x32_f16(al[m], bf[n], acc[m][n + 2], 0, 0, 0);
                acc[m][n + 2] = __builtin_amdgcn_mfma_f32_16x16x32_f16(ah[m], bf[n], acc[m][n + 2], 0, 0, 0);
            }
        }
        __builtin_amdgcn_s_setprio(0);
        asm volatile("s_waitcnt vmcnt(0)" ::: "memory");
        __builtin_amdgcn_s_barrier();
        cb = 20480 - cb;
    }

    #pragma unroll
    for (int m = 0; m < 4; ++m) {
        #pragma unroll
        for (int n = 0; n < 4; ++n) {
            int col = col0 + wc * 64 + n * 16 + r;
            float b = bias[col];
            #pragma unroll
            for (int v = 0; v < 4; ++v) {
                int row = row0 + wr * 64 + m * 16 + q * 4 + v;
                C[(size_t)row * N + col] = acc[m][n][v] + b;
            }
        }
    }
}

// ---------------------------------------------------------------------------
// RoPE + scale + fp16 convert + head-major relayout. (unchanged)
// ---------------------------------------------------------------------------
__global__ __launch_bounds__(256) void rope_split_kernel(
    const float* __restrict__ qkv, const float* __restrict__ cos_t,
    const float* __restrict__ sin_t,
    ushort* __restrict__ qf, ushort* __restrict__ kf,
    ushort* __restrict__ vt)
{
    __shared__ float s_v[64][84];
    const int tid = threadIdx.x;
    const int b = blockIdx.z, h = blockIdx.y;
    const int n0 = blockIdx.x * 64;
    const int bh = b * HEADS + h;

    #pragma unroll
    for (int i = 0; i < 5; ++i) {
        int u = tid + i * 256;
        int n = u / 20, c = u % 20;
        const float* src = qkv + (size_t)(b * NN + n0 + n) * 3840 + 2 * HIDDEN + h * HD + c * 4;
        *(float4*)(&s_v[n][c * 4]) = *(const float4*)src;
    }

    for (int u = tid; u < 640; u += 256) {
        int n = u / 10, p = u % 10;
        int d = p * 4;
        int ng = n0 + n;
        size_t rowb = (size_t)(b * NN + ng) * 3840;
        float4 c0 = *(const float4*)(cos_t + ng * HD + d);
        float4 c1 = *(const float4*)(cos_t + ng * HD + d + HALF);
        float4 s0 = *(const float4*)(sin_t + ng * HD + d);
        float4 s1 = *(const float4*)(sin_t + ng * HD + d + HALF);
        size_t qo = ((size_t)bh * NN + ng) * 96;
        {
            float4 x0 = *(const float4*)(qkv + rowb + h * HD + d);
            float4 x1 = *(const float4*)(qkv + rowb + h * HD + d + HALF);
            ushort4 h4a, h4b;
            h4a.x = f2h((x0.x * c0.x - x1.x * s0.x) * QSCALE);
            h4a.y = f2h((x0.y * c0.y - x1.y * s0.y) * QSCALE);
            h4a.z = f2h((x0.z * c0.z - x1.z * s0.z) * QSCALE);
            h4a.w = f2h((x0.w * c0.w - x1.w * s0.w) * QSCALE);
            h4b.x = f2h((x1.x * c1.x + x0.x * s1.x) * QSCALE);
            h4b.y = f2h((x1.y * c1.y + x0.y * s1.y) * QSCALE);
            h4b.z = f2h((x1.z * c1.z + x0.z * s1.z) * QSCALE);
            h4b.w = f2h((x1.w * c1.w + x0.w * s1.w) * QSCALE);
            *(ushort4*)(qf + qo + d) = h4a;
            *(ushort4*)(qf + qo + d + HALF) = h4b;
        }
        {
            float4 x0 = *(const float4*)(qkv + rowb + HIDDEN + h * HD + d);
            float4 x1 = *(const float4*)(qkv + rowb + HIDDEN + h * HD + d + HALF);
            ushort4 h4a, h4b;
            h4a.x = f2h(x0.x * c0.x - x1.x * s0.x);
            h4a.y = f2h(x0.y * c0.y - x1.y * s0.y);
            h4a.z = f2h(x0.z * c0.z - x1.z * s0.z);
            h4a.w = f2h(x0.w * c0.w - x1.w * s0.w);
            h4b.x = f2h(x1.x * c1.x + x0.x * s1.x);
            h4b.y = f2h(x1.y * c1.y + x0.y * s1.y);
            h4b.z = f2h(x1.z * c1.z + x0.z * s1.z);
            h4b.w = f2h(x1.w * c1.w + x0.w * s1.w);
            *(ushort4*)(kf + qo + d) = h4a;
            *(ushort4*)(kf + qo + d + HALF) = h4b;
        }
    }

    {
        int which = tid >> 7;
        int u = tid & 127;
        int n = u >> 1, part = u & 1;
        size_t o = ((size_t)bh * NN + n0 + n) * 96 + 80 + part * 8;
        uint4 z = {0u, 0u, 0u, 0u};
        if (which == 0) *(uint4*)(qf + o) = z;
        else            *(uint4*)(kf + o) = z;
    }
    __syncthreads();

    for (int u = tid; u < 320; u += 256) {
        int d = u >> 2, nc = u & 3;
        ushort hs[16];
        #pragma unroll
        for (int kk = 0; kk < 16; ++kk)
            hs[kk] = f2h(s_v[nc * 16 + kk][d]);
        size_t o = ((size_t)bh * HD + d) * NN + n0 + nc * 16;
        uint4 w0, w1;
        w0.x = (uint)hs[0] | ((uint)hs[1] << 16);
        w0.y = (uint)hs[2] | ((uint)hs[3] << 16);
        w0.z = (uint)hs[4] | ((uint)hs[5] << 16);
        w0.w = (uint)hs[6] | ((uint)hs[7] << 16);
        w1.x = (uint)hs[8] | ((uint)hs[9] << 16);
        w1.y = (uint)hs[10] | ((uint)hs[11] << 16);
        w1.z = (uint)hs[12] | ((uint)hs[13] << 16);
        w1.w = (uint)hs[14] | ((uint)hs[15] << 16);
        *(uint4*)(vt + o) = w0;
        *(uint4*)(vt + o + 8) = w1;
    }
}

// ---------------------------------------------------------------------------
// MFMA flash attention v9: Q-block 256 (wave owns 32 q-rows, 2 subtiles).
// Rationale: v6/v8 validated model = LDS-read-port-bound; K(12 b128) +
// V(10 b128) per wave-iter is the floor and is paid per 16 q-rows. v9 reuses
// each kbf/vbf register fragment for TWO q-subtiles -> K/V read traffic per
// output halves. Grid (NN/256, HEADS, BB) = 256 blocks = 1/CU.
// LDS 86016 B: bufs 2x26624 + p_s [256][64] 32768. launch_bounds(512,2)
// (1 block/CU anyway; let regalloc breathe). Same swapped-QK score layout,
// P-write/read involution, and per-row accumulation order as v8 (P and oacc
// bit-identical per row; l sum order ulp-level as before).
// ---------------------------------------------------------------------------
__global__ __launch_bounds__(512, 2) void attn_mfma_kernel(
    const ushort* __restrict__ qf, const ushort* __restrict__ kf,
    const ushort* __restrict__ vt,
    ushort* __restrict__ ao_hi, ushort* __restrict__ ao_lo)
{
    __shared__ __align__(16) ushort lds[43008];   // 86016 B
    // buf0: [0,13312) = K0 [64][128] (8192 u16) | V0 [80][64] (5120 u16)
    // buf1: [13312,26624)
    // p_s : [26624,43008) = [256 rows][64 fp16], 16B-granule swizzled
    ushort* p_s = lds + 26624;

    const int tid = threadIdx.x;
    const int wave = tid >> 6, lane = tid & 63;
    const int quad = lane >> 4, r = lane & 15;
    const int b = blockIdx.z, h = blockIdx.y;
    const int bh = b * HEADS + h;
    const int q0 = blockIdx.x * 256;

    const size_t kb = (size_t)bh * NN * 96;
    const size_t vb = (size_t)bh * HD * NN;

    // ---- staging precompute: seg s = wave + 8*i, i = 0..3 (26 segs) ----
    const ushort* gptr[4];
    int ldso[4];
    #pragma unroll
    for (int i = 0; i < 4; ++i) {
        int s = wave + i * 8;
        if (s < 16) {
            int row = s * 4 + (lane >> 4);
            int t = lane & 15;
            int g = t ^ (row & 7);
            if (g >= 12) g = 0;
            gptr[i] = kf + kb + (size_t)row * 96 + g * 8;
            ldso[i] = s * 512 + lane * 8;
        } else if (s < 26) {
            int ts = s - 16;
            gptr[i] = vt + vb + (size_t)(ts * 8 + (lane >> 3)) * NN
                      + (size_t)(((lane & 7) ^ (lane >> 3)) * 8);
            ldso[i] = 8192 + ts * 512 + lane * 8;
        } else {
            gptr[i] = nullptr;
            ldso[i] = 0;
        }
    }

    // Q a-frags: two 16-row subtiles, rows wave*32 + mt*16 + r
    f16x8 qfr[2][3];
    #pragma unroll
    for (int mt = 0; mt < 2; ++mt)
        #pragma unroll
        for (int c = 0; c < 3; ++c) {
            size_t o = ((size_t)bh * NN + q0 + wave * 32 + mt * 16 + r) * 96 + c * 32 + quad * 8;
            qfr[mt][c] = *(const f16x8*)(qf + o);
        }

    f32x4 oacc[2][5] = {};
    float l_lane[2] = {0.0f, 0.0f};

    // per-lane p_s row bases (wave-private rows [wave*32, wave*32+32))
    const int prow0 = (wave * 32 + r) * 64;
    const int prow1 = (wave * 32 + 16 + r) * 64;
    const int r7 = r & 7;

    // prologue: stage tile 0 -> buf0
    #pragma unroll
    for (int i = 0; i < 4; ++i) {
        int s = wave + i * 8;
        if (s < 26) {
            __builtin_amdgcn_global_load_lds((const AS1 unsigned int*)gptr[i],
                (AS3 unsigned int*)(lds + ldso[i]), 16, 0, 0);
            gptr[i] += (s < 16) ? 6144 : 64;
        }
    }
    asm volatile("s_waitcnt vmcnt(0)" ::: "memory");
    __builtin_amdgcn_s_barrier();

    int cur = 0;
    for (int j0 = 0; j0 < NN; j0 += 64) {
        const int nxt = 13312 - cur;
        if (j0 + 64 < NN) {
            #pragma unroll
            for (int i = 0; i < 4; ++i) {
                int s = wave + i * 8;
                if (s < 26) {
                    __builtin_amdgcn_global_load_lds((const AS1 unsigned int*)gptr[i],
                        (AS3 unsigned int*)(lds + nxt + ldso[i]), 16, 0, 0);
                    gptr[i] += (s < 16) ? 6144 : 64;
                }
            }
        }

        const ushort* k_s = lds + cur;
        const _Float16* v_s = (const _Float16*)(lds + cur + 8192);

        // QK^T swapped: sc[mt][jt][v] = S[q=wave*32+mt*16+r][kt=jt*16+quad*4+v]
        // kbf read ONCE per jt, reused for both q-subtiles (the point of v9).
        f32x4 sc[2][4] = {};
        __builtin_amdgcn_s_setprio(1);
        #pragma unroll
        for (int jt = 0; jt < 4; ++jt) {
            f16x8 kbf[3];
            int j = jt * 16 + r;
            #pragma unroll
            for (int c = 0; c < 3; ++c) {
                int ch = (c * 4 + quad) ^ r7;
                kbf[c] = *(const f16x8*)(k_s + j * 128 + ch * 8);
            }
            #pragma unroll
            for (int c = 0; c < 3; ++c) {
                sc[0][jt] = __builtin_amdgcn_mfma_f32_16x16x32_f16(kbf[c], qfr[0][c], sc[0][jt], 0, 0, 0);
                sc[1][jt] = __builtin_amdgcn_mfma_f32_16x16x32_f16(kbf[c], qfr[1][c], sc[1][jt], 0, 0, 0);
            }
        }
        __builtin_amdgcn_s_setprio(0);

        // softmax: lane owns q-rows' k-slots; pack 4 fp16 -> one b64 write/jt
        #pragma unroll
        for (int mt = 0; mt < 2; ++mt) {
            const int prow = mt ? prow1 : prow0;
            #pragma unroll
            for (int jt = 0; jt < 4; ++jt) {
                float p0 = __builtin_amdgcn_exp2f(sc[mt][jt][0]);
                float p1 = __builtin_amdgcn_exp2f(sc[mt][jt][1]);
                float p2 = __builtin_amdgcn_exp2f(sc[mt][jt][2]);
                float p3 = __builtin_amdgcn_exp2f(sc[mt][jt][3]);
                l_lane[mt] += p0;
                l_lane[mt] += p1;
                l_lane[mt] += p2;
                l_lane[mt] += p3;
                uint2 w;
                w.x = (uint)f2h(p0) | ((uint)f2h(p1) << 16);
                w.y = (uint)f2h(p2) | ((uint)f2h(p3) << 16);
                int off = prow + (((jt * 2 + (quad >> 1)) ^ r7) * 8) + (quad & 1) * 4;
                *(uint2*)(p_s + off) = w;
            }
        }

        // P a-frags (same involution)
        f16x8 pa[2][2];
        #pragma unroll
        for (int cc = 0; cc < 2; ++cc) {
            int gp = ((cc * 4 + quad) ^ r7) * 8;
            pa[0][cc] = *(const f16x8*)(p_s + prow0 + gp);
            pa[1][cc] = *(const f16x8*)(p_s + prow1 + gp);
        }

        // PV: vbf read ONCE per (dt,cc), reused for both q-subtiles
        __builtin_amdgcn_s_setprio(1);
        #pragma unroll
        for (int dt = 0; dt < 5; ++dt)
            #pragma unroll
            for (int cc = 0; cc < 2; ++cc) {
                int ck = (cc * 4 + quad) ^ r7;
                f16x8 vbf = *(const f16x8*)(v_s + (dt * 16 + r) * 64 + ck * 8);
                oacc[0][dt] = __builtin_amdgcn_mfma_f32_16x16x32_f16(pa[0][cc], vbf, oacc[0][dt], 0, 0, 0);
                oacc[1][dt] = __builtin_amdgcn_mfma_f32_16x16x32_f16(pa[1][cc], vbf, oacc[1][dt], 0, 0, 0);
            }
        __builtin_amdgcn_s_setprio(0);

        asm volatile("s_waitcnt vmcnt(0)" ::: "memory");
        __builtin_amdgcn_s_barrier();
        cur = nxt;
    }

    // l reduction per subtile (quad-copies hold disjoint k-slots)
    float inv_l[2][4];
    #pragma unroll
    for (int mt = 0; mt < 2; ++mt) {
        float lt = l_lane[mt];
        lt += __shfl_xor(lt, 16);
        lt += __shfl_xor(lt, 32);
        #pragma unroll
        for (int v = 0; v < 4; ++v)
            inv_l[mt][v] = 1.0f / __shfl(lt, quad * 4 + v);
    }

    // epilogue: normalize + fp16-split into LDS [256][80] hi/lo, uint4 stores
    __syncthreads();
    #pragma unroll
    for (int mt = 0; mt < 2; ++mt)
        #pragma unroll
        for (int v = 0; v < 4; ++v) {
            int row = wave * 32 + mt * 16 + quad * 4 + v;
            #pragma unroll
            for (int dt = 0; dt < 5; ++dt) {
                float o = oacc[mt][dt][v] * inv_l[mt][v];
                ushort hh, ll;
                splitf16(o, hh, ll);
                lds[row * 80 + dt * 16 + r] = hh;
                lds[20480 + row * 80 + dt * 16 + r] = ll;
            }
        }
    __syncthreads();
    {
        size_t gbase = ((size_t)b * NN + q0) * HIDDEN + h * HD;
        #pragma unroll
        for (int i = 0; i < 10; ++i) {
            int u = tid + i * 512;            // 0..5119
            int plane = u / 2560, idx = u % 2560;
            int row = idx / 10, part = idx % 10;
            uint4 w = *(const uint4*)(lds + plane * 20480 + idx * 8);
            ushort* dst = (plane ? ao_lo : ao_hi) + gbase + (size_t)row * HIDDEN + part * 8;
            *(uint4*)dst = w;
        }
    }
}

// ---------------------------------------------------------------------------
extern "C" void kernel_launch(void* const* d_in, const int* in_sizes, int n_in,
                              void* d_out, int out_size, void* d_ws, size_t ws_size,
                              hipStream_t stream)
{
    const float* x      = (const float*)d_in[0];
    const float* cos_t  = (const float*)d_in[1];
    const float* sin_t  = (const float*)d_in[2];
    const float* qkv_w  = (const float*)d_in[3];
    const float* qkv_b  = (const float*)d_in[4];
    const float* proj_w = (const float*)d_in[5];
    const float* proj_b = (const float*)d_in[6];
    float* out = (float*)d_out;

    char* ws = (char*)d_ws;
    // layout (bytes), phase-based reuse:
    //   [0, 62914560)           qkv fp32 (gemm1 out; dead after rope_split)
    //       -> ao_hi @0 (10485760), ao_lo @10485760 (attn out, fp16 hi/lo)
    //   [62914560, 72744960)    wT fp16 (qkv_w^T); after gemm1:
    //       -> vt fp16 @62914560 (10485760, ends 73400320)
    //   [82575360, 103546880)   x split fp16 hi/lo (gemm1 A); after gemm1:
    //       -> qf @83886080 (12582912), kf @96468992 (ends 109051904)
    //   [109051904, 112328704)  pT fp16 (proj_w^T)
    float*  qkv   = (float*)ws;
    ushort* ao_hi = (ushort*)ws;
    ushort* ao_lo = (ushort*)(ws + 10485760);
    ushort* wT    = (ushort*)(ws + 62914560);
    ushort* vt    = (ushort*)(ws + 62914560);
    ushort* a_hi  = (ushort*)(ws + 82575360);
    ushort* a_lo  = (ushort*)(ws + 93061120);
    ushort* q_f   = (ushort*)(ws + 83886080);
    ushort* k_f   = (ushort*)(ws + 96468992);
    ushort* pT    = (ushort*)(ws + 109051904);

    // 1) fused prep: split x -> hi/lo, transpose qkv_w -> wT, proj_w -> pT
    prep_kernel<<<dim3(11520), 256, 0, stream>>>(
        x, a_hi, a_lo, qkv_w, wT, proj_w, pT);

    // 2) qkv = x @ qkv_w + qkv_b   (256x128 v2 4-phase — measured best)
    gemm_f16x2_256x128_kernel<<<dim3((MROWS / 256) * (3 * HIDDEN / 128)), 512, 0, stream>>>(
        a_hi, a_lo, wT, qkv_b, qkv, MROWS, 3 * HIDDEN, HIDDEN, 3 * HIDDEN / 128);

    // 3) RoPE + fp16 relayout (overwrites wT and x-split regions — both dead)
    rope_split_kernel<<<dim3(NN / 64, HEADS, BB), 256, 0, stream>>>(
        qkv, cos_t, sin_t, q_f, k_f, vt);

    // 4) MFMA flash attention v9 (Q-block 256: K/V frag reuse across 2
    //    q-subtiles halves LDS read traffic per output; 256 blocks = 1/CU)
    attn_mfma_kernel<<<dim3(NN / 256, HEADS, BB), 512, 0, stream>>>(
        q_f, k_f, vt, ao_hi, ao_lo);

    // 5) out = attn_out @ proj_w + proj_b  (128^2 double-buffered, ~27 us)
    gemm_f16x2_kernel<<<dim3(HIDDEN / BN, MROWS / BM), 256, 0, stream>>>(
        ao_hi, ao_lo, pT, proj_b, out, MROWS, HIDDEN, HIDDEN);
}

// Round 14
// 297.468 us; speedup vs baseline: 1.0336x; 1.0139x over previous
//
#include <hip/hip_runtime.h>
#include <hip/hip_bf16.h>
#include <math.h>

#define HIDDEN 1280
#define HEADS 16
#define HD 80           // head dim
#define HALF 40
#define BB 2
#define NN 2048
#define MROWS (BB * NN) // 4096
// 1/sqrt(80) * log2(e): scores come out in log2 domain -> exp2 directly
#define QSCALE ((float)(0.11180339887498949 * 1.4426950408889634))

typedef __attribute__((ext_vector_type(8))) _Float16 f16x8;
typedef __attribute__((ext_vector_type(4))) float f32x4;

#define AS1 __attribute__((address_space(1)))
#define AS3 __attribute__((address_space(3)))

// Split fp32 into fp16 hi + fp16 lo (hi+lo carries ~22 mantissa bits).
__device__ __forceinline__ void splitf16(float x, ushort& hi, ushort& lo) {
    _Float16 h = (_Float16)x;
    _Float16 l = (_Float16)(x - (float)h);
    hi = __builtin_bit_cast(ushort, h);
    lo = __builtin_bit_cast(ushort, l);
}

__device__ __forceinline__ ushort f2h(float x) {
    _Float16 h = (_Float16)x;
    return __builtin_bit_cast(ushort, h);
}

// ---------------------------------------------------------------------------
// Fused prep kernel: split x + transpose qkv_w + transpose proj_w.
// ---------------------------------------------------------------------------
__device__ __forceinline__ void tsplit_tile(
    const float* __restrict__ W, ushort* __restrict__ T, int K, int N,
    int n0, int k0, float (*s)[33], int tid)
{
    {
        int tn = tid & 31, tk = tid >> 5;
        #pragma unroll
        for (int i = 0; i < 4; ++i)
            s[tk + i * 8][tn] = W[(size_t)(k0 + tk + i * 8) * N + n0 + tn];
    }
    __syncthreads();
    {
        int tk = tid & 31, tn = tid >> 5;
        #pragma unroll
        for (int i = 0; i < 4; ++i)
            T[(size_t)(n0 + tn + i * 8) * K + k0 + tk] = f2h(s[tk][tn + i * 8]);
    }
}

__global__ __launch_bounds__(256) void prep_kernel(
    const float* __restrict__ x, ushort* __restrict__ a_hi,
    ushort* __restrict__ a_lo,
    const float* __restrict__ qkv_w, ushort* __restrict__ wT,
    const float* __restrict__ proj_w, ushort* __restrict__ pT)
{
    __shared__ float s[32][33];
    const int tid = threadIdx.x;
    const int id = blockIdx.x;

    if (id < 5120) {
        int i = id * 256 + tid;
        float4 v = ((const float4*)x)[i];
        ushort4 h, l;
        splitf16(v.x, h.x, l.x);
        splitf16(v.y, h.y, l.y);
        splitf16(v.z, h.z, l.z);
        splitf16(v.w, h.w, l.w);
        ((ushort4*)a_hi)[i] = h;
        ((ushort4*)a_lo)[i] = l;
    } else if (id < 9920) {
        int id2 = id - 5120;
        int n0 = (id2 % 120) * 32, k0 = (id2 / 120) * 32;
        tsplit_tile(qkv_w, wT, HIDDEN, 3 * HIDDEN, n0, k0, s, tid);
    } else {
        int id2 = id - 9920;
        int n0 = (id2 % 40) * 32, k0 = (id2 / 40) * 32;
        tsplit_tile(proj_w, pT, HIDDEN, HIDDEN, n0, k0, s, tid);
    }
}

// ---------------------------------------------------------------------------
// fp16x2 MFMA GEMM 128x128 v2 (proj GEMM) — round-8 winner (kept): double-
// buffered (48 KB, 3 blocks/CU), stage(t+1) first, compiler-scheduled frag
// reads/MFMAs, one vmcnt(0)+barrier per tile. ~27 us.
// ---------------------------------------------------------------------------
#define BM 128
#define BN 128
#define BK 32

__global__ __launch_bounds__(256) void gemm_f16x2_kernel(
    const ushort* __restrict__ Ahi, const ushort* __restrict__ Alo,
    const ushort* __restrict__ Bh,
    const float* __restrict__ bias, float* __restrict__ C,
    int M, int N, int K)
{
    __shared__ __align__(16) ushort lds[2 * 12288];   // 49152 B

    const int tid = threadIdx.x;
    const int wid = tid >> 6;
    const int lane = tid & 63;
    const int col0 = blockIdx.x * BN;
    const int row0 = blockIdx.y * BM;
    const int wy = wid >> 1, wx = wid & 1;
    const int lrow = lane >> 2;
    const int lchunk = lane & 3;
    const int q = lane >> 4;
    const int r = lane & 15;

    const ushort* gsrc[6];
    int ldst[6];
    #pragma unroll
    for (int i = 0; i < 6; ++i) {
        int s = wid + i * 4;
        int tile = s >> 3, t = s & 7;
        const ushort* src = (tile == 0) ? Ahi : (tile == 1) ? Alo : Bh;
        int srow = (tile < 2) ? row0 : col0;
        gsrc[i] = src + (size_t)(srow + t * 16 + lrow) * K + lchunk * 8;
        ldst[i] = tile * 4096 + t * 512 + lane * 8;
    }

    const int NT = K / BK;

    #pragma unroll
    for (int i = 0; i < 6; ++i)
        __builtin_amdgcn_global_load_lds((const AS1 unsigned int*)(gsrc[i]),
            (AS3 unsigned int*)(lds + ldst[i]), 16, 0, 0);
    asm volatile("s_waitcnt vmcnt(0)" ::: "memory");
    __builtin_amdgcn_s_barrier();

    f32x4 acc[4][4] = {};
    int cb = 0;

    for (int t = 0; t < NT; ++t) {
        const ushort* base = lds + cb;
        ushort* nbuf = lds + (12288 - cb);
        if (t + 1 < NT) {
            const int ko = (t + 1) * BK;
            #pragma unroll
            for (int i = 0; i < 6; ++i)
                __builtin_amdgcn_global_load_lds((const AS1 unsigned int*)(gsrc[i] + ko),
                    (AS3 unsigned int*)(nbuf + ldst[i]), 16, 0, 0);
        }

        f16x8 ah[4], al[4], bf[4];
        #pragma unroll
        for (int i = 0; i < 4; ++i) {
            int arow = wy * 64 + i * 16 + r;
            ah[i] = *(const f16x8*)(base + 0 * 4096 + arow * 32 + q * 8);
            al[i] = *(const f16x8*)(base + 1 * 4096 + arow * 32 + q * 8);
            int brow = wx * 64 + i * 16 + r;
            bf[i] = *(const f16x8*)(base + 2 * 4096 + brow * 32 + q * 8);
        }
        #pragma unroll
        for (int i = 0; i < 4; ++i) {
            #pragma unroll
            for (int j = 0; j < 4; ++j) {
                acc[i][j] = __builtin_amdgcn_mfma_f32_16x16x32_f16(al[i], bf[j], acc[i][j], 0, 0, 0);
                acc[i][j] = __builtin_amdgcn_mfma_f32_16x16x32_f16(ah[i], bf[j], acc[i][j], 0, 0, 0);
            }
        }

        asm volatile("s_waitcnt vmcnt(0)" ::: "memory");
        __builtin_amdgcn_s_barrier();
        cb = 12288 - cb;
    }

    #pragma unroll
    for (int i = 0; i < 4; ++i) {
        #pragma unroll
        for (int j = 0; j < 4; ++j) {
            int col = col0 + wx * 64 + j * 16 + r;
            float b = bias[col];
            #pragma unroll
            for (int v = 0; v < 4; ++v) {
                int row = row0 + wy * 64 + i * 16 + q * 4 + v;
                C[(size_t)row * N + col] = acc[i][j][v] + b;
            }
        }
    }
}

// ---------------------------------------------------------------------------
// 128x256 4-wave fp16x2 GEMM v5 (QKV GEMM). Model-driven redesign:
// v2's 82 us == serialized LDS(2304) + MFMA(2484) cyc/CU/tile; MfmaUtil 43%
// == 2484/4788. The controllable ratio is READS-PER-MFMA: wave tile 64x64
// costs 12 b128 per 32 MFMAs (0.375); wave tile 64x128 costs 16 per 64
// (0.25, -33% LDS issue). Structure = round-8 MEASURED WINNER (gemm2's):
// 4-wave block, double-buffer, stage(t+1) issued first, frag reads + 64
// MFMAs left to compiler's counted-lgkmcnt scheduling (no pins — at 4 waves
// that beat the pinned skeleton), ONE vmcnt(0)+barrier per tile.
// Block 128x256, BK=32, LDS 2x32KB=64KB -> 2 blocks/CU; grid 480 (%8==0,
// T1 swizzle). acc[4][8]=128 AGPR + 16 frags: ~220 regs -> 2 waves/SIMD.
// Per-acc-element chain unchanged (al then ah, K ascending) -> bit-identical.
// ---------------------------------------------------------------------------
__global__ __launch_bounds__(256, 2) void gemm_f16x2_128x256_kernel(
    const ushort* __restrict__ Ahi, const ushort* __restrict__ Alo,
    const ushort* __restrict__ Bh,
    const float* __restrict__ bias, float* __restrict__ C,
    int M, int N, int K, int nbx)
{
    __shared__ __align__(16) ushort lds[2 * 16384];   // 65536 B

    const int tid = threadIdx.x;
    const int wid = tid >> 6;
    const int lane = tid & 63;
    const int q = lane >> 4, r = lane & 15;
    const int wr = wid >> 1;      // 0..1: 64-row band
    const int wc = wid & 1;       // 0..1: 128-col band

    // T1: XCD-aware block swizzle (grid = 480, %8 == 0)
    int id = blockIdx.x;
    {
        int nwg = gridDim.x;
        if ((nwg & 7) == 0) {
            int c = nwg >> 3;
            id = (id & 7) * c + (id >> 3);
        }
    }
    const int row0 = (id / nbx) * 128;
    const int col0 = (id % nbx) * 256;

    // --- staging: 32 segs (Ahi 8, Alo 8, B 16), 8 per wave ---
    // seg layout: 512 u16 each; dest linear, source chunk pre-swizzled with
    // the same (row>>1)&3 involution as the read side.
    const ushort* gsrc[8];
    int ldst[8];
    #pragma unroll
    for (int i = 0; i < 8; ++i) {
        int s = wid + i * 4;          // 0..31
        const ushort* srcb;
        int t, rbase;
        int dof;
        if (s < 8)       { srcb = Ahi; t = s;      rbase = row0; dof = 0; }
        else if (s < 16) { srcb = Alo; t = s - 8;  rbase = row0; dof = 4096; }
        else             { srcb = Bh;  t = s - 16; rbase = col0; dof = 8192; }
        int rloc = t * 16 + (lane >> 2);
        int sl = (lane & 3) ^ ((rloc >> 1) & 3);
        gsrc[i] = srcb + (size_t)(rbase + rloc) * K + sl * 8;
        ldst[i] = dof + t * 512 + lane * 8;
    }

    const int NT = K / 32;

    // prologue: stage tile 0 -> buf0
    #pragma unroll
    for (int i = 0; i < 8; ++i)
        __builtin_amdgcn_global_load_lds((const AS1 unsigned int*)(gsrc[i]),
            (AS3 unsigned int*)(lds + ldst[i]), 16, 0, 0);
    asm volatile("s_waitcnt vmcnt(0)" ::: "memory");
    __builtin_amdgcn_s_barrier();

    const int soff = (q ^ ((r >> 1) & 3)) * 8;
    const int arow0 = wr * 64 + r;       // + m*16
    const int brow0 = wc * 128 + r;      // + n*16

    f32x4 acc[4][8] = {};
    int cb = 0;

    for (int t = 0; t < NT; ++t) {
        const ushort* A0 = lds + cb;
        const ushort* A1 = lds + cb + 4096;
        const ushort* Bp = lds + cb + 8192;
        ushort* nbuf = lds + (16384 - cb);

        // stage next tile first (latency hidden under this tile's compute)
        if (t + 1 < NT) {
            const int ko = (t + 1) * 32;
            #pragma unroll
            for (int i = 0; i < 8; ++i)
                __builtin_amdgcn_global_load_lds((const AS1 unsigned int*)(gsrc[i] + ko),
                    (AS3 unsigned int*)(nbuf + ldst[i]), 16, 0, 0);
        }

        // frag reads + MFMAs, compiler-scheduled (round-8 winner pattern)
        f16x8 ah[4], al[4], bf[8];
        #pragma unroll
        for (int m = 0; m < 4; ++m) {
            int ro = (arow0 + m * 16) * 32 + soff;
            ah[m] = *(const f16x8*)(A0 + ro);
            al[m] = *(const f16x8*)(A1 + ro);
        }
        #pragma unroll
        for (int n = 0; n < 8; ++n)
            bf[n] = *(const f16x8*)(Bp + (brow0 + n * 16) * 32 + soff);

        __builtin_amdgcn_s_setprio(1);
        #pragma unroll
        for (int m = 0; m < 4; ++m) {
            #pragma unroll
            for (int n = 0; n < 8; ++n) {
                acc[m][n] = __builtin_amdgcn_mfma_f32_16x16x32_f16(al[m], bf[n], acc[m][n], 0, 0, 0);
                acc[m][n] = __builtin_amdgcn_mfma_f32_16x16x32_f16(ah[m], bf[n], acc[m][n], 0, 0, 0);
            }
        }
        __builtin_amdgcn_s_setprio(0);

        // single sync point per tile: staged loads had the whole tile in flight
        asm volatile("s_waitcnt vmcnt(0)" ::: "memory");
        __builtin_amdgcn_s_barrier();
        cb = 16384 - cb;
    }

    // epilogue: bias + store
    #pragma unroll
    for (int m = 0; m < 4; ++m) {
        #pragma unroll
        for (int n = 0; n < 8; ++n) {
            int col = col0 + wc * 128 + n * 16 + r;
            float b = bias[col];
            #pragma unroll
            for (int v = 0; v < 4; ++v) {
                int row = row0 + wr * 64 + m * 16 + q * 4 + v;
                C[(size_t)row * N + col] = acc[m][n][v] + b;
            }
        }
    }
}

// ---------------------------------------------------------------------------
// RoPE + scale + fp16 convert + head-major relayout. (unchanged)
// ---------------------------------------------------------------------------
__global__ __launch_bounds__(256) void rope_split_kernel(
    const float* __restrict__ qkv, const float* __restrict__ cos_t,
    const float* __restrict__ sin_t,
    ushort* __restrict__ qf, ushort* __restrict__ kf,
    ushort* __restrict__ vt)
{
    __shared__ float s_v[64][84];
    const int tid = threadIdx.x;
    const int b = blockIdx.z, h = blockIdx.y;
    const int n0 = blockIdx.x * 64;
    const int bh = b * HEADS + h;

    #pragma unroll
    for (int i = 0; i < 5; ++i) {
        int u = tid + i * 256;
        int n = u / 20, c = u % 20;
        const float* src = qkv + (size_t)(b * NN + n0 + n) * 3840 + 2 * HIDDEN + h * HD + c * 4;
        *(float4*)(&s_v[n][c * 4]) = *(const float4*)src;
    }

    for (int u = tid; u < 640; u += 256) {
        int n = u / 10, p = u % 10;
        int d = p * 4;
        int ng = n0 + n;
        size_t rowb = (size_t)(b * NN + ng) * 3840;
        float4 c0 = *(const float4*)(cos_t + ng * HD + d);
        float4 c1 = *(const float4*)(cos_t + ng * HD + d + HALF);
        float4 s0 = *(const float4*)(sin_t + ng * HD + d);
        float4 s1 = *(const float4*)(sin_t + ng * HD + d + HALF);
        size_t qo = ((size_t)bh * NN + ng) * 96;
        {
            float4 x0 = *(const float4*)(qkv + rowb + h * HD + d);
            float4 x1 = *(const float4*)(qkv + rowb + h * HD + d + HALF);
            ushort4 h4a, h4b;
            h4a.x = f2h((x0.x * c0.x - x1.x * s0.x) * QSCALE);
            h4a.y = f2h((x0.y * c0.y - x1.y * s0.y) * QSCALE);
            h4a.z = f2h((x0.z * c0.z - x1.z * s0.z) * QSCALE);
            h4a.w = f2h((x0.w * c0.w - x1.w * s0.w) * QSCALE);
            h4b.x = f2h((x1.x * c1.x + x0.x * s1.x) * QSCALE);
            h4b.y = f2h((x1.y * c1.y + x0.y * s1.y) * QSCALE);
            h4b.z = f2h((x1.z * c1.z + x0.z * s1.z) * QSCALE);
            h4b.w = f2h((x1.w * c1.w + x0.w * s1.w) * QSCALE);
            *(ushort4*)(qf + qo + d) = h4a;
            *(ushort4*)(qf + qo + d + HALF) = h4b;
        }
        {
            float4 x0 = *(const float4*)(qkv + rowb + HIDDEN + h * HD + d);
            float4 x1 = *(const float4*)(qkv + rowb + HIDDEN + h * HD + d + HALF);
            ushort4 h4a, h4b;
            h4a.x = f2h(x0.x * c0.x - x1.x * s0.x);
            h4a.y = f2h(x0.y * c0.y - x1.y * s0.y);
            h4a.z = f2h(x0.z * c0.z - x1.z * s0.z);
            h4a.w = f2h(x0.w * c0.w - x1.w * s0.w);
            h4b.x = f2h(x1.x * c1.x + x0.x * s1.x);
            h4b.y = f2h(x1.y * c1.y + x0.y * s1.y);
            h4b.z = f2h(x1.z * c1.z + x0.z * s1.z);
            h4b.w = f2h(x1.w * c1.w + x0.w * s1.w);
            *(ushort4*)(kf + qo + d) = h4a;
            *(ushort4*)(kf + qo + d + HALF) = h4b;
        }
    }

    {
        int which = tid >> 7;
        int u = tid & 127;
        int n = u >> 1, part = u & 1;
        size_t o = ((size_t)bh * NN + n0 + n) * 96 + 80 + part * 8;
        uint4 z = {0u, 0u, 0u, 0u};
        if (which == 0) *(uint4*)(qf + o) = z;
        else            *(uint4*)(kf + o) = z;
    }
    __syncthreads();

    for (int u = tid; u < 320; u += 256) {
        int d = u >> 2, nc = u & 3;
        ushort hs[16];
        #pragma unroll
        for (int kk = 0; kk < 16; ++kk)
            hs[kk] = f2h(s_v[nc * 16 + kk][d]);
        size_t o = ((size_t)bh * HD + d) * NN + n0 + nc * 16;
        uint4 w0, w1;
        w0.x = (uint)hs[0] | ((uint)hs[1] << 16);
        w0.y = (uint)hs[2] | ((uint)hs[3] << 16);
        w0.z = (uint)hs[4] | ((uint)hs[5] << 16);
        w0.w = (uint)hs[6] | ((uint)hs[7] << 16);
        w1.x = (uint)hs[8] | ((uint)hs[9] << 16);
        w1.y = (uint)hs[10] | ((uint)hs[11] << 16);
        w1.z = (uint)hs[12] | ((uint)hs[13] << 16);
        w1.w = (uint)hs[14] | ((uint)hs[15] << 16);
        *(uint4*)(vt + o) = w0;
        *(uint4*)(vt + o + 8) = w1;
    }
}

// ---------------------------------------------------------------------------
// MFMA flash attention v9 (round-12: Q-block 256, K/V frag reuse; ~76 us).
// ---------------------------------------------------------------------------
__global__ __launch_bounds__(512, 2) void attn_mfma_kernel(
    const ushort* __restrict__ qf, const ushort* __restrict__ kf,
    const ushort* __restrict__ vt,
    ushort* __restrict__ ao_hi, ushort* __restrict__ ao_lo)
{
    __shared__ __align__(16) ushort lds[43008];   // 86016 B
    ushort* p_s = lds + 26624;

    const int tid = threadIdx.x;
    const int wave = tid >> 6, lane = tid & 63;
    const int quad = lane >> 4, r = lane & 15;
    const int b = blockIdx.z, h = blockIdx.y;
    const int bh = b * HEADS + h;
    const int q0 = blockIdx.x * 256;

    const size_t kb = (size_t)bh * NN * 96;
    const size_t vb = (size_t)bh * HD * NN;

    const ushort* gptr[4];
    int ldso[4];
    #pragma unroll
    for (int i = 0; i < 4; ++i) {
        int s = wave + i * 8;
        if (s < 16) {
            int row = s * 4 + (lane >> 4);
            int t = lane & 15;
            int g = t ^ (row & 7);
            if (g >= 12) g = 0;
            gptr[i] = kf + kb + (size_t)row * 96 + g * 8;
            ldso[i] = s * 512 + lane * 8;
        } else if (s < 26) {
            int ts = s - 16;
            gptr[i] = vt + vb + (size_t)(ts * 8 + (lane >> 3)) * NN
                      + (size_t)(((lane & 7) ^ (lane >> 3)) * 8);
            ldso[i] = 8192 + ts * 512 + lane * 8;
        } else {
            gptr[i] = nullptr;
            ldso[i] = 0;
        }
    }

    f16x8 qfr[2][3];
    #pragma unroll
    for (int mt = 0; mt < 2; ++mt)
        #pragma unroll
        for (int c = 0; c < 3; ++c) {
            size_t o = ((size_t)bh * NN + q0 + wave * 32 + mt * 16 + r) * 96 + c * 32 + quad * 8;
            qfr[mt][c] = *(const f16x8*)(qf + o);
        }

    f32x4 oacc[2][5] = {};
    float l_lane[2] = {0.0f, 0.0f};

    const int prow0 = (wave * 32 + r) * 64;
    const int prow1 = (wave * 32 + 16 + r) * 64;
    const int r7 = r & 7;

    #pragma unroll
    for (int i = 0; i < 4; ++i) {
        int s = wave + i * 8;
        if (s < 26) {
            __builtin_amdgcn_global_load_lds((const AS1 unsigned int*)gptr[i],
                (AS3 unsigned int*)(lds + ldso[i]), 16, 0, 0);
            gptr[i] += (s < 16) ? 6144 : 64;
        }
    }
    asm volatile("s_waitcnt vmcnt(0)" ::: "memory");
    __builtin_amdgcn_s_barrier();

    int cur = 0;
    for (int j0 = 0; j0 < NN; j0 += 64) {
        const int nxt = 13312 - cur;
        if (j0 + 64 < NN) {
            #pragma unroll
            for (int i = 0; i < 4; ++i) {
                int s = wave + i * 8;
                if (s < 26) {
                    __builtin_amdgcn_global_load_lds((const AS1 unsigned int*)gptr[i],
                        (AS3 unsigned int*)(lds + nxt + ldso[i]), 16, 0, 0);
                    gptr[i] += (s < 16) ? 6144 : 64;
                }
            }
        }

        const ushort* k_s = lds + cur;
        const _Float16* v_s = (const _Float16*)(lds + cur + 8192);

        f32x4 sc[2][4] = {};
        __builtin_amdgcn_s_setprio(1);
        #pragma unroll
        for (int jt = 0; jt < 4; ++jt) {
            f16x8 kbf[3];
            int j = jt * 16 + r;
            #pragma unroll
            for (int c = 0; c < 3; ++c) {
                int ch = (c * 4 + quad) ^ r7;
                kbf[c] = *(const f16x8*)(k_s + j * 128 + ch * 8);
            }
            #pragma unroll
            for (int c = 0; c < 3; ++c) {
                sc[0][jt] = __builtin_amdgcn_mfma_f32_16x16x32_f16(kbf[c], qfr[0][c], sc[0][jt], 0, 0, 0);
                sc[1][jt] = __builtin_amdgcn_mfma_f32_16x16x32_f16(kbf[c], qfr[1][c], sc[1][jt], 0, 0, 0);
            }
        }
        __builtin_amdgcn_s_setprio(0);

        #pragma unroll
        for (int mt = 0; mt < 2; ++mt) {
            const int prow = mt ? prow1 : prow0;
            #pragma unroll
            for (int jt = 0; jt < 4; ++jt) {
                float p0 = __builtin_amdgcn_exp2f(sc[mt][jt][0]);
                float p1 = __builtin_amdgcn_exp2f(sc[mt][jt][1]);
                float p2 = __builtin_amdgcn_exp2f(sc[mt][jt][2]);
                float p3 = __builtin_amdgcn_exp2f(sc[mt][jt][3]);
                l_lane[mt] += p0;
                l_lane[mt] += p1;
                l_lane[mt] += p2;
                l_lane[mt] += p3;
                uint2 w;
                w.x = (uint)f2h(p0) | ((uint)f2h(p1) << 16);
                w.y = (uint)f2h(p2) | ((uint)f2h(p3) << 16);
                int off = prow + (((jt * 2 + (quad >> 1)) ^ r7) * 8) + (quad & 1) * 4;
                *(uint2*)(p_s + off) = w;
            }
        }

        f16x8 pa[2][2];
        #pragma unroll
        for (int cc = 0; cc < 2; ++cc) {
            int gp = ((cc * 4 + quad) ^ r7) * 8;
            pa[0][cc] = *(const f16x8*)(p_s + prow0 + gp);
            pa[1][cc] = *(const f16x8*)(p_s + prow1 + gp);
        }

        __builtin_amdgcn_s_setprio(1);
        #pragma unroll
        for (int dt = 0; dt < 5; ++dt)
            #pragma unroll
            for (int cc = 0; cc < 2; ++cc) {
                int ck = (cc * 4 + quad) ^ r7;
                f16x8 vbf = *(const f16x8*)(v_s + (dt * 16 + r) * 64 + ck * 8);
                oacc[0][dt] = __builtin_amdgcn_mfma_f32_16x16x32_f16(pa[0][cc], vbf, oacc[0][dt], 0, 0, 0);
                oacc[1][dt] = __builtin_amdgcn_mfma_f32_16x16x32_f16(pa[1][cc], vbf, oacc[1][dt], 0, 0, 0);
            }
        __builtin_amdgcn_s_setprio(0);

        asm volatile("s_waitcnt vmcnt(0)" ::: "memory");
        __builtin_amdgcn_s_barrier();
        cur = nxt;
    }

    float inv_l[2][4];
    #pragma unroll
    for (int mt = 0; mt < 2; ++mt) {
        float lt = l_lane[mt];
        lt += __shfl_xor(lt, 16);
        lt += __shfl_xor(lt, 32);
        #pragma unroll
        for (int v = 0; v < 4; ++v)
            inv_l[mt][v] = 1.0f / __shfl(lt, quad * 4 + v);
    }

    __syncthreads();
    #pragma unroll
    for (int mt = 0; mt < 2; ++mt)
        #pragma unroll
        for (int v = 0; v < 4; ++v) {
            int row = wave * 32 + mt * 16 + quad * 4 + v;
            #pragma unroll
            for (int dt = 0; dt < 5; ++dt) {
                float o = oacc[mt][dt][v] * inv_l[mt][v];
                ushort hh, ll;
                splitf16(o, hh, ll);
                lds[row * 80 + dt * 16 + r] = hh;
                lds[20480 + row * 80 + dt * 16 + r] = ll;
            }
        }
    __syncthreads();
    {
        size_t gbase = ((size_t)b * NN + q0) * HIDDEN + h * HD;
        #pragma unroll
        for (int i = 0; i < 10; ++i) {
            int u = tid + i * 512;            // 0..5119
            int plane = u / 2560, idx = u % 2560;
            int row = idx / 10, part = idx % 10;
            uint4 w = *(const uint4*)(lds + plane * 20480 + idx * 8);
            ushort* dst = (plane ? ao_lo : ao_hi) + gbase + (size_t)row * HIDDEN + part * 8;
            *(uint4*)dst = w;
        }
    }
}

// ---------------------------------------------------------------------------
extern "C" void kernel_launch(void* const* d_in, const int* in_sizes, int n_in,
                              void* d_out, int out_size, void* d_ws, size_t ws_size,
                              hipStream_t stream)
{
    const float* x      = (const float*)d_in[0];
    const float* cos_t  = (const float*)d_in[1];
    const float* sin_t  = (const float*)d_in[2];
    const float* qkv_w  = (const float*)d_in[3];
    const float* qkv_b  = (const float*)d_in[4];
    const float* proj_w = (const float*)d_in[5];
    const float* proj_b = (const float*)d_in[6];
    float* out = (float*)d_out;

    char* ws = (char*)d_ws;
    // layout (bytes), phase-based reuse:
    //   [0, 62914560)           qkv fp32 (gemm1 out; dead after rope_split)
    //       -> ao_hi @0 (10485760), ao_lo @10485760 (attn out, fp16 hi/lo)
    //   [62914560, 72744960)    wT fp16 (qkv_w^T); after gemm1:
    //       -> vt fp16 @62914560 (10485760, ends 73400320)
    //   [82575360, 103546880)   x split fp16 hi/lo (gemm1 A); after gemm1:
    //       -> qf @83886080 (12582912), kf @96468992 (ends 109051904)
    //   [109051904, 112328704)  pT fp16 (proj_w^T)
    float*  qkv   = (float*)ws;
    ushort* ao_hi = (ushort*)ws;
    ushort* ao_lo = (ushort*)(ws + 10485760);
    ushort* wT    = (ushort*)(ws + 62914560);
    ushort* vt    = (ushort*)(ws + 62914560);
    ushort* a_hi  = (ushort*)(ws + 82575360);
    ushort* a_lo  = (ushort*)(ws + 93061120);
    ushort* q_f   = (ushort*)(ws + 83886080);
    ushort* k_f   = (ushort*)(ws + 96468992);
    ushort* pT    = (ushort*)(ws + 109051904);

    // 1) fused prep: split x -> hi/lo, transpose qkv_w -> wT, proj_w -> pT
    prep_kernel<<<dim3(11520), 256, 0, stream>>>(
        x, a_hi, a_lo, qkv_w, wT, proj_w, pT);

    // 2) qkv = x @ qkv_w + qkv_b   (128x256 v5: reads-per-MFMA 0.25,
    //    round-8-winner sync structure; grid 32*15=480, %8==0)
    gemm_f16x2_128x256_kernel<<<dim3((MROWS / 128) * (3 * HIDDEN / 256)), 256, 0, stream>>>(
        a_hi, a_lo, wT, qkv_b, qkv, MROWS, 3 * HIDDEN, HIDDEN, 3 * HIDDEN / 256);

    // 3) RoPE + fp16 relayout (overwrites wT and x-split regions — both dead)
    rope_split_kernel<<<dim3(NN / 64, HEADS, BB), 256, 0, stream>>>(
        qkv, cos_t, sin_t, q_f, k_f, vt);

    // 4) MFMA flash attention v9 (Q-block 256)
    attn_mfma_kernel<<<dim3(NN / 256, HEADS, BB), 512, 0, stream>>>(
        q_f, k_f, vt, ao_hi, ao_lo);

    // 5) out = attn_out @ proj_w + proj_b  (128^2 double-buffered, ~27 us)
    gemm_f16x2_kernel<<<dim3(HIDDEN / BN, MROWS / BM), 256, 0, stream>>>(
        ao_hi, ao_lo, pT, proj_b, out, MROWS, HIDDEN, HIDDEN);
}